// Round 20
// baseline (107.270 us; speedup 1.0000x reference)
//
#include <hip/hip_runtime.h>
#include <hip/hip_bf16.h>

// Problem constants
#define DM    1024
#define NH    16
#define DKH   64
#define BB    2
#define SS    2048
#define MROWS (BB*SS)   // 4096

typedef __attribute__((ext_vector_type(8))) short s16x8;
typedef __attribute__((ext_vector_type(4))) float f32x4;
typedef unsigned short u16;
typedef unsigned int u32;

#if __has_builtin(__builtin_amdgcn_exp2f)
#define EXP2(x) __builtin_amdgcn_exp2f(x)
#else
#define EXP2(x) exp2f(x)
#endif

__device__ inline u16 f2b(float f) {
    __hip_bfloat16 h = __float2bfloat16(f);
    return __builtin_bit_cast(u16, h);
}
__device__ inline float b2f(u16 u) {
    return __bfloat162float(__builtin_bit_cast(__hip_bfloat16, u));
}

__device__ inline f32x4 mfma16(s16x8 a, s16x8 b, f32x4 c) {
    return __builtin_amdgcn_mfma_f32_16x16x32_bf16(a, b, c, 0, 0, 0);
}

__device__ inline void gload_lds16(const u16* g, u16* l) {
    __builtin_amdgcn_global_load_lds((const __attribute__((address_space(1))) void*)g,
                                     (__attribute__((address_space(3))) void*)l, 16, 0, 0);
}

// ---------------- prep: fp32 -> bf16 casts + RoPE table (fused) ----------------
__global__ void k_prep(const float* __restrict__ x, const float* __restrict__ wq,
                       const float* __restrict__ wk, const float* __restrict__ wv,
                       const float* __restrict__ wo, const int* __restrict__ pos,
                       u16* __restrict__ xb, u16* __restrict__ wqkvb, u16* __restrict__ wob,
                       float2* __restrict__ tab) {
    int64_t i0 = (int64_t)blockIdx.x * blockDim.x + threadIdx.x;
    int64_t strd = (int64_t)gridDim.x * blockDim.x;
    const float4* x4 = (const float4*)x;
    ushort4* xb4 = (ushort4*)xb;
    for (int64_t t = i0; t < (int64_t)MROWS*DM/4; t += strd) {
        float4 v = x4[t];
        xb4[t] = make_ushort4(f2b(v.x), f2b(v.y), f2b(v.z), f2b(v.w));
    }
    const float4* q4 = (const float4*)wq;
    const float4* k4 = (const float4*)wk;
    const float4* v4 = (const float4*)wv;
    const float4* o4 = (const float4*)wo;
    ushort4* w4  = (ushort4*)wqkvb;
    ushort4* wo4 = (ushort4*)wob;
    const int64_t nw4 = (int64_t)DM*DM/4;   // 262144
    for (int64_t t = i0; t < nw4; t += strd) {
        float4 a = q4[t]; w4[t]         = make_ushort4(f2b(a.x), f2b(a.y), f2b(a.z), f2b(a.w));
        float4 b = k4[t]; w4[nw4 + t]   = make_ushort4(f2b(b.x), f2b(b.y), f2b(b.z), f2b(b.w));
        float4 c = v4[t]; w4[2*nw4 + t] = make_ushort4(f2b(c.x), f2b(c.y), f2b(c.z), f2b(c.w));
        float4 d = o4[t]; wo4[t]        = make_ushort4(f2b(d.x), f2b(d.y), f2b(d.z), f2b(d.w));
    }
    // RoPE cos/sin table: SS*32 entries
    for (int64_t t = i0; t < SS * 32; t += strd) {
        int s = (int)(t >> 5), j = (int)(t & 31);
        float p = (float)pos[s];
        float freq = powf(10000.0f, -(float)(2 * j) * (1.0f / 64.0f));
        float a = p * freq;
        tab[t] = make_float2(cosf(a), sinf(a));
    }
}

// ---------------- QKV projection GEMM: BK=32, 2-phase dbuf + COUNTED vmcnt ----------
// T4: each wave waits only its own previous tile's 4 loads (vmcnt(4)); prefetch
// stays in flight across raw s_barriers. Two raw barriers per K-step:
//  X (pre-compute): all waves' tile-t loads landed (each waited vmcnt(4) first);
//  Y (post-compute): all buf reads consumed (by MFMAs) before next overwrite lands.
__global__ void __launch_bounds__(256)
k_gemm_qkv(const u16* __restrict__ xb, const u16* __restrict__ wqkvb,
           const float2* __restrict__ tab,
           u16* __restrict__ Qb, u16* __restrict__ Kb, u16* __restrict__ Vt) {
    __shared__ u16 As[2][4096], Bs[2][4096];
    const int m0 = blockIdx.x * 128, n0 = blockIdx.y * 128;
    const int tid  = threadIdx.x;
    const int lane = tid & 63;
    const int wid  = tid >> 6;
    const int wm = (wid >> 1) << 6;
    const int wn = (wid & 1) << 6;
    const int lr = lane & 15;
    const int lg = lane >> 4;
    const int lk = lg << 3;

    f32x4 acc[4][4];
#pragma unroll
    for (int mi = 0; mi < 4; mi++)
#pragma unroll
        for (int ni = 0; ni < 4; ni++) acc[mi][ni] = f32x4{0.f, 0.f, 0.f, 0.f};

#define QSTAGE(kk, bb)                                                         \
    {                                                                          \
        _Pragma("unroll")                                                      \
        for (int iss = 0; iss < 2; ++iss) {                                    \
            int idx = iss * 2048 + tid * 8;                                    \
            int row = idx >> 5;                                                \
            int col = idx & 31;                                                \
            gload_lds16(xb    + (int64_t)(m0 + row) * 1024 + (kk) + col,       \
                        &As[bb][idx]);                                         \
            gload_lds16(wqkvb + (int64_t)(n0 + row) * 1024 + (kk) + col,       \
                        &Bs[bb][idx]);                                         \
        }                                                                      \
    }

    QSTAGE(0, 0)
    int cur = 0;
    for (int k0 = 0; k0 < 1024; k0 += 32) {
        if (k0 + 32 < 1024) {
            QSTAGE(k0 + 32, cur ^ 1)   // prefetch next tile (4 loads/thread)
            asm volatile("s_waitcnt vmcnt(4)" ::: "memory");   // own tile-t loads done
        } else {
            asm volatile("s_waitcnt vmcnt(0)" ::: "memory");
        }
        __builtin_amdgcn_sched_barrier(0);
        __builtin_amdgcn_s_barrier();          // X: all waves' tile-t data in LDS
        s16x8 af[4], bf[4];
#pragma unroll
        for (int mi = 0; mi < 4; mi++)
            af[mi] = *(const s16x8*)(&As[cur][0] + (wm + mi * 16 + lr) * 32 + lk);
#pragma unroll
        for (int ni = 0; ni < 4; ni++)
            bf[ni] = *(const s16x8*)(&Bs[cur][0] + (wn + ni * 16 + lr) * 32 + lk);
        __builtin_amdgcn_s_setprio(1);
#pragma unroll
        for (int mi = 0; mi < 4; mi++)
#pragma unroll
            for (int ni = 0; ni < 4; ni++)
                acc[mi][ni] = mfma16(af[mi], bf[ni], acc[mi][ni]);
        __builtin_amdgcn_s_setprio(0);
        __builtin_amdgcn_s_barrier();          // Y: reads of cur consumed everywhere
        cur ^= 1;
    }
#undef QSTAGE

    // ---- fused RoPE + V-transpose epilogue (unchanged) ----
    const float QSC = 0.18033688011112042f;  // (1/8) * log2(e)
    const bool evenlane = (lr & 1) == 0;
#pragma unroll
    for (int mi = 0; mi < 4; mi++) {
        const int gm0 = m0 + wm + mi * 16 + lg * 4;
        const int b = gm0 >> 11;
        const int s0 = gm0 & 2047;
#pragma unroll
        for (int ni = 0; ni < 4; ni++) {
            int gn = n0 + wn + ni * 16 + lr;
            int which = gn >> 10;
            int nn = gn & 1023;
            int h = nn >> 6, d = nn & 63;
            if (which == 2) {
                ushort4 pk;
                pk.x = f2b(acc[mi][ni][0]);
                pk.y = f2b(acc[mi][ni][1]);
                pk.z = f2b(acc[mi][ni][2]);
                pk.w = f2b(acc[mi][ni][3]);
                *(ushort4*)(Vt + ((int64_t)(b * 16 + h)) * (2048 * 64)
                               + (int64_t)d * 2048 + s0) = pk;
            } else {
                u16* dst = (which == 0) ? Qb : Kb;
                float scl = (which == 0) ? QSC : 1.0f;
                int j = d >> 1;
#pragma unroll
                for (int r = 0; r < 4; r++) {
                    float v = acc[mi][ni][r];
                    float partner = __shfl_xor(v, 1, 64);
                    float2 cs = tab[(s0 + r) * 32 + j];
                    float outv = evenlane ? (cs.x * v - cs.y * partner)
                                          : (cs.y * partner + cs.x * v);
                    dst[(((int64_t)(b * 16 + h)) * 2048 + (s0 + r)) * 64 + d] =
                        f2b(outv * scl);
                }
            }
        }
    }
}

// ---------------- causal flash attention, single-buffered K/V, 24KB LDS ----------
// (R15/R17 structure verbatim — measured best of the attn family.)
__global__ void __launch_bounds__(128)
k_attn(const u16* __restrict__ Q, const u16* __restrict__ K,
       const u16* __restrict__ Vt, u16* __restrict__ O,
       u16* __restrict__ Op1, float* __restrict__ l0, float* __restrict__ l1) {
    __shared__ __align__(16) u16 Kl[4096];      // 64 keys x 64 d, swizzled (8KB)
    __shared__ __align__(16) u16 Vl[4096];      // 64 d x 64 keys, swizzled (8KB)
    __shared__ __align__(16) char Pbuf[2][4096];
    const int tid  = threadIdx.x;
    const int lane = tid & 63;
    const int wid  = tid >> 6;                  // 0..1
    const int lr = lane & 15;
    const int lg = lane >> 4;
    const int lk = lg * 8;
    const int G  = blockIdx.x >> 5;             // 0..47
    const int bh = blockIdx.x & 31;             // bh -> XCD bh%8
    int c, seg, split;
    if (G < 8)       { c = 15 - G;            seg = 0;     split = 0; }
    else if (G < 40) { int j = G - 8; c = 31 - (j >> 1); seg = j & 1; split = 1; }
    else             { c = 47 - G;            seg = 0;     split = 0; }
    const int T  = c + 1;                       // total tiles for this chunk
    const int h0 = T >> 1;
    const int t0 = (split && seg == 1) ? h0 : 0;
    const int nT = split ? (seg == 0 ? h0 : T - h0) : T;
    const int hasDiag = !(split && seg == 0);
    const int q0 = c * 64 + wid * 32;           // this wave's first q row
    const int64_t base = (int64_t)bh * (2048 * 64);
    const u16* Qp = Q  + base;
    const u16* Kp = K  + base;
    const u16* Vp = Vt + base;   // [d][s] layout

    s16x8 aq[2][2];
#pragma unroll
    for (int mi = 0; mi < 2; ++mi)
#pragma unroll
        for (int db = 0; db < 2; ++db)
            aq[mi][db] = *(const s16x8*)(Qp + (q0 + mi * 16 + lr) * 64 + db * 32 + lk);

    f32x4 acco[2][4];
    f32x4 accl[2];
#pragma unroll
    for (int mi = 0; mi < 2; ++mi) {
        accl[mi] = f32x4{0.f, 0.f, 0.f, 0.f};
#pragma unroll
        for (int df = 0; df < 4; ++df) acco[mi][df] = f32x4{0.f, 0.f, 0.f, 0.f};
    }
    const s16x8 ones = {(short)0x3F80, (short)0x3F80, (short)0x3F80, (short)0x3F80,
                        (short)0x3F80, (short)0x3F80, (short)0x3F80, (short)0x3F80};
    const int swz = (lr & 7) << 4;
    char* PwB = &Pbuf[wid][0];

#define STAGE(t)                                                               \
    {                                                                          \
        const u16* ks = Kp + (t) * 4096;                                       \
        const u16* vs = Vp + (t) * 64;                                         \
        _Pragma("unroll")                                                      \
        for (int p = 0; p < 4; ++p) {                                          \
            int o = p * 2048 + tid * 16;                                       \
            int row = o >> 7;                                                  \
            int cc = ((o >> 4) & 7) ^ (row & 7);                               \
            gload_lds16(ks + row * 64 + cc * 8,                                \
                        (u16*)((char*)&Kl[0] + o));                            \
            gload_lds16(vs + row * 2048 + cc * 8,                              \
                        (u16*)((char*)&Vl[0] + o));                            \
        }                                                                      \
    }

    STAGE(t0)

    for (int u = 0; u < nT; ++u) {
        const int t = t0 + u;
        asm volatile("s_waitcnt vmcnt(0)" ::: "memory");
        __syncthreads();                         // staged tile visible to both waves
        {
            const char* Kc = (const char*)&Kl[0];
            const char* Vc = (const char*)&Vl[0];
            // K fragments from LDS (swizzled)
            s16x8 bk[4][2];
#pragma unroll
            for (int kb = 0; kb < 4; ++kb)
#pragma unroll
                for (int db = 0; db < 2; ++db) {
                    int row = kb * 16 + lr;
                    int cc = (db * 4 + lg) ^ (row & 7);
                    bk[kb][db] = *(const s16x8*)(Kc + row * 128 + cc * 16);
                }
            // QK^T (SWAPPED: A=K, B=Q -> C[row=key_local, col=q_local])
            f32x4 sc[2][4];
            __builtin_amdgcn_s_setprio(1);
#pragma unroll
            for (int mi = 0; mi < 2; ++mi)
#pragma unroll
                for (int kb = 0; kb < 4; ++kb) {
                    sc[mi][kb] = f32x4{0.f, 0.f, 0.f, 0.f};
#pragma unroll
                    for (int db = 0; db < 2; ++db)
                        sc[mi][kb] = mfma16(bk[kb][db], aq[mi][db], sc[mi][kb]);
                }
            __builtin_amdgcn_s_setprio(0);
            // exp2 + packed P write
            const int k0 = t << 6;
            if (hasDiag && u == nT - 1) {
#pragma unroll
                for (int mi = 0; mi < 2; ++mi) {
                    const int prow = mi * 16 + lr;
                    const int qg = q0 + prow;
                    const int pswz = (prow & 7) << 4;
#pragma unroll
                    for (int kb = 0; kb < 4; ++kb) {
                        const int kg = k0 + kb * 16 + lg * 4;
                        float p0 = EXP2((kg     <= qg) ? sc[mi][kb][0] : -3.0e38f);
                        float p1 = EXP2((kg + 1 <= qg) ? sc[mi][kb][1] : -3.0e38f);
                        float p2 = EXP2((kg + 2 <= qg) ? sc[mi][kb][2] : -3.0e38f);
                        float p3 = EXP2((kg + 3 <= qg) ? sc[mi][kb][3] : -3.0e38f);
                        u32 lo = (u32)f2b(p0) | ((u32)f2b(p1) << 16);
                        u32 hi = (u32)f2b(p2) | ((u32)f2b(p3) << 16);
                        int bo = (prow << 7) + kb * 32 + (lg << 3);
                        *(uint2*)(PwB + (bo ^ pswz)) = make_uint2(lo, hi);
                    }
                }
            } else {
#pragma unroll
                for (int mi = 0; mi < 2; ++mi) {
                    const int prow = mi * 16 + lr;
                    const int pswz = (prow & 7) << 4;
#pragma unroll
                    for (int kb = 0; kb < 4; ++kb) {
                        float p0 = EXP2(sc[mi][kb][0]);
                        float p1 = EXP2(sc[mi][kb][1]);
                        float p2 = EXP2(sc[mi][kb][2]);
                        float p3 = EXP2(sc[mi][kb][3]);
                        u32 lo = (u32)f2b(p0) | ((u32)f2b(p1) << 16);
                        u32 hi = (u32)f2b(p2) | ((u32)f2b(p3) << 16);
                        int bo = (prow << 7) + kb * 32 + (lg << 3);
                        *(uint2*)(PwB + (bo ^ pswz)) = make_uint2(lo, hi);
                    }
                }
            }
            // V fragments from LDS (swizzled)
            s16x8 bv[2][4];
#pragma unroll
            for (int kc = 0; kc < 2; ++kc)
#pragma unroll
                for (int df = 0; df < 4; ++df) {
                    int row = df * 16 + lr;
                    int cc = (kc * 4 + lg) ^ (row & 7);
                    bv[kc][df] = *(const s16x8*)(Vc + row * 128 + cc * 16);
                }
            asm volatile("s_waitcnt lgkmcnt(0)" ::: "memory");
            // PV + row-sum via all-ones MFMA
            __builtin_amdgcn_s_setprio(1);
#pragma unroll
            for (int mi = 0; mi < 2; ++mi)
#pragma unroll
                for (int kc = 0; kc < 2; ++kc) {
                    int ro = ((mi * 16 + lr) << 7) + (kc << 6) + (lg << 4);
                    s16x8 ap = *(const s16x8*)(PwB + (ro ^ swz));
#pragma unroll
                    for (int df = 0; df < 4; ++df)
                        acco[mi][df] = mfma16(ap, bv[kc][df], acco[mi][df]);
                    accl[mi] = mfma16(ap, ones, accl[mi]);
                }
            __builtin_amdgcn_s_setprio(0);
        }
        __syncthreads();                         // both waves done reading K/V LDS
        if (u + 1 < nT) STAGE(t0 + u + 1)
    }
#undef STAGE

    // ---- epilogue ----
    const int b = bh >> 4, h = bh & 15;
    if (!split) {
#pragma unroll
        for (int mi = 0; mi < 2; ++mi) {
            float inv[4];
#pragma unroll
            for (int r = 0; r < 4; ++r) inv[r] = 1.0f / accl[mi][r];
#pragma unroll
            for (int df = 0; df < 4; ++df)
#pragma unroll
                for (int r = 0; r < 4; ++r) {
                    const int s = q0 + mi * 16 + lg * 4 + r;
                    const int d = df * 16 + lr;
                    O[(((int64_t)(b * 2048 + s)) * 16 + h) * 64 + d] =
                        f2b(acco[mi][df][r] * inv[r]);
                }
        }
    } else {
        const int cc = c - 16;
        const int rg0 = (bh * 16 + cc) * 64 + wid * 32;  // row-group base
        if (seg == 0) {
#pragma unroll
            for (int mi = 0; mi < 2; ++mi) {
#pragma unroll
                for (int df = 0; df < 4; ++df)
#pragma unroll
                    for (int r = 0; r < 4; ++r) {
                        const int s = q0 + mi * 16 + lg * 4 + r;
                        const int d = df * 16 + lr;
                        O[(((int64_t)(b * 2048 + s)) * 16 + h) * 64 + d] =
                            f2b(acco[mi][df][r]);
                    }
                if (lr == 0)
#pragma unroll
                    for (int r = 0; r < 4; ++r)
                        l0[rg0 + mi * 16 + lg * 4 + r] = accl[mi][r];
            }
        } else {
#pragma unroll
            for (int mi = 0; mi < 2; ++mi) {
#pragma unroll
                for (int df = 0; df < 4; ++df)
#pragma unroll
                    for (int r = 0; r < 4; ++r) {
                        const int row = wid * 32 + mi * 16 + lg * 4 + r;
                        const int d = df * 16 + lr;
                        Op1[((int64_t)((bh * 16 + cc) * 64 + row)) * 64 + d] =
                            f2b(acco[mi][df][r]);
                    }
                if (lr == 0)
#pragma unroll
                    for (int r = 0; r < 4; ++r)
                        l1[rg0 + mi * 16 + lg * 4 + r] = accl[mi][r];
            }
        }
    }
}

// ---------------- combine split-KV partials: O = (O + Op1) / (l0 + l1) ----------------
__global__ void __launch_bounds__(256)
k_combine(u16* __restrict__ O, const u16* __restrict__ Op1,
          const float* __restrict__ l0, const float* __restrict__ l1) {
    int i = blockIdx.x * 256 + threadIdx.x;     // 0..262143
    int rg = i >> 3;                            // (bh,cc,row) 0..32767
    int d0 = (i & 7) << 3;
    int bh = rg >> 10;
    int cc = (rg >> 6) & 15;
    int row = rg & 63;
    float inv = 1.0f / (l0[rg] + l1[rg]);
    int b = bh >> 4, h = bh & 15;
    int s = (16 + cc) * 64 + row;
    u16* op = O + (((int64_t)(b * 2048 + s)) * 16 + h) * 64 + d0;
    const u16* sp = Op1 + (int64_t)rg * 64 + d0;
    s16x8 a = *(const s16x8*)op;
    s16x8 bb = *(const s16x8*)sp;
    u16 outv[8];
#pragma unroll
    for (int j = 0; j < 8; ++j)
        outv[j] = f2b((b2f((u16)a[j]) + b2f((u16)bb[j])) * inv);
    *(s16x8*)op = *(s16x8*)&outv[0];
}

// ---------------- output projection GEMM: 64x128 tiles, 2-phase dbuf + counted vmcnt ----
__global__ void __launch_bounds__(256)
k_gemm_out(const u16* __restrict__ Ob, const u16* __restrict__ wob, float* __restrict__ out) {
    __shared__ u16 As[2][2048], Bs[2][4096];   // 64x32 A, 128x32 B, double-buffered
    const int m0 = blockIdx.x * 64, n0 = blockIdx.y * 128;
    const int tid  = threadIdx.x;
    const int lane = tid & 63;
    const int wid  = tid >> 6;          // 4 waves, each 64x32 output (wn = wid*32)
    const int wn = wid << 5;
    const int lr = lane & 15;
    const int lk = (lane >> 4) << 3;
    f32x4 acc[4][2];
#pragma unroll
    for (int mi = 0; mi < 4; mi++)
#pragma unroll
        for (int ni = 0; ni < 2; ni++) acc[mi][ni] = f32x4{0.f, 0.f, 0.f, 0.f};

#define OSTAGE(kk, bb)                                                         \
    {                                                                          \
        {   int idx = tid * 8;                                                 \
            int row = idx >> 5, col = idx & 31;                                \
            gload_lds16(Ob + (int64_t)(m0 + row) * 1024 + (kk) + col,          \
                        &As[bb][idx]); }                                       \
        _Pragma("unroll")                                                      \
        for (int iss = 0; iss < 2; ++iss) {                                    \
            int idx = iss * 2048 + tid * 8;                                    \
            int row = idx >> 5, col = idx & 31;                                \
            gload_lds16(wob + (int64_t)(n0 + row) * 1024 + (kk) + col,         \
                        &Bs[bb][idx]);                                         \
        }                                                                      \
    }

    OSTAGE(0, 0)
    int cur = 0;
    for (int k0 = 0; k0 < 1024; k0 += 32) {
        if (k0 + 32 < 1024) {
            OSTAGE(k0 + 32, cur ^ 1)   // 3 loads/thread
            asm volatile("s_waitcnt vmcnt(3)" ::: "memory");
        } else {
            asm volatile("s_waitcnt vmcnt(0)" ::: "memory");
        }
        __builtin_amdgcn_sched_barrier(0);
        __builtin_amdgcn_s_barrier();          // X: tile-t data in LDS
        s16x8 af[4], bf[2];
#pragma unroll
        for (int mi = 0; mi < 4; mi++)
            af[mi] = *(const s16x8*)(&As[cur][0] + (mi * 16 + lr) * 32 + lk);
#pragma unroll
        for (int ni = 0; ni < 2; ni++)
            bf[ni] = *(const s16x8*)(&Bs[cur][0] + (wn + ni * 16 + lr) * 32 + lk);
        __builtin_amdgcn_s_setprio(1);
#pragma unroll
        for (int mi = 0; mi < 4; mi++)
#pragma unroll
            for (int ni = 0; ni < 2; ni++)
                acc[mi][ni] = mfma16(af[mi], bf[ni], acc[mi][ni]);
        __builtin_amdgcn_s_setprio(0);
        __builtin_amdgcn_s_barrier();          // Y: reads consumed
        cur ^= 1;
    }
#undef OSTAGE

    const int lg = lane >> 4;
#pragma unroll
    for (int mi = 0; mi < 4; mi++)
#pragma unroll
        for (int ni = 0; ni < 2; ni++) {
            int gn = n0 + wn + ni * 16 + lr;
#pragma unroll
            for (int r = 0; r < 4; r++) {
                int gm = m0 + mi * 16 + lg * 4 + r;
                out[(int64_t)gm * 1024 + gn] = acc[mi][ni][r];
            }
        }
}

extern "C" void kernel_launch(void* const* d_in, const int* in_sizes, int n_in,
                              void* d_out, int out_size, void* d_ws, size_t ws_size,
                              hipStream_t stream) {
    const float* x  = (const float*)d_in[0];
    const int* pos  = (const int*)d_in[1];
    const float* wq = (const float*)d_in[2];
    const float* wk = (const float*)d_in[3];
    const float* wv = (const float*)d_in[4];
    const float* wo = (const float*)d_in[5];
    float* out = (float*)d_out;

    char* w = (char*)d_ws;
    u16* xb    = (u16*)w;    w += (size_t)MROWS * DM * 2;        // 8 MB
    u16* wqkvb = (u16*)w;    w += (size_t)3 * DM * DM * 2;       // 6 MB
    u16* wob   = (u16*)w;    w += (size_t)DM * DM * 2;           // 2 MB
    float2* tab = (float2*)w; w += (size_t)SS * 32 * sizeof(float2); // 512 KB
    u16* Qb = (u16*)w;       w += (size_t)MROWS * DM * 2;        // 8 MB
    u16* Kb = (u16*)w;       w += (size_t)MROWS * DM * 2;        // 8 MB
    u16* Vt = (u16*)w;       w += (size_t)MROWS * DM * 2;        // 8 MB
    u16* Ob = (u16*)w;                                           // 8 MB
    // split-KV scratch carved from xb (dead after k_gemm_qkv): 4MB + 128KB + 128KB
    u16*   Op1 = xb;                                  // 32*16*64*64 bf16 = 4 MB
    float* l0  = (float*)((char*)xb + (4 << 20));     // 128 KB
    float* l1  = (float*)((char*)xb + (4 << 20) + (128 << 10));

    k_prep<<<dim3(1024), dim3(256), 0, stream>>>(x, wq, wk, wv, wo, pos,
                                                 xb, wqkvb, wob, tab);
    k_gemm_qkv<<<dim3(32, 24), dim3(256), 0, stream>>>(xb, wqkvb, tab, Qb, Kb, Vt);
    k_attn<<<dim3(1536), dim3(128), 0, stream>>>(Qb, Kb, Vt, Ob, Op1, l0, l1);
    k_combine<<<dim3(1024), dim3(256), 0, stream>>>(Ob, Op1, l0, l1);
    k_gemm_out<<<dim3(64, 8), dim3(256), 0, stream>>>(Ob, wob, out);
}

// Round 21
// 105.238 us; speedup vs baseline: 1.0193x; 1.0193x over previous
//
#include <hip/hip_runtime.h>
#include <hip/hip_bf16.h>

// Problem constants
#define DM    1024
#define NH    16
#define DKH   64
#define BB    2
#define SS    2048
#define MROWS (BB*SS)   // 4096

typedef __attribute__((ext_vector_type(8))) short s16x8;
typedef __attribute__((ext_vector_type(4))) float f32x4;
typedef unsigned short u16;
typedef unsigned int u32;

#if __has_builtin(__builtin_amdgcn_exp2f)
#define EXP2(x) __builtin_amdgcn_exp2f(x)
#else
#define EXP2(x) exp2f(x)
#endif

__device__ inline u16 f2b(float f) {
    __hip_bfloat16 h = __float2bfloat16(f);
    return __builtin_bit_cast(u16, h);
}
__device__ inline float b2f(u16 u) {
    return __bfloat162float(__builtin_bit_cast(__hip_bfloat16, u));
}

__device__ inline f32x4 mfma16(s16x8 a, s16x8 b, f32x4 c) {
    return __builtin_amdgcn_mfma_f32_16x16x32_bf16(a, b, c, 0, 0, 0);
}

__device__ inline void gload_lds16(const u16* g, u16* l) {
    __builtin_amdgcn_global_load_lds((const __attribute__((address_space(1))) void*)g,
                                     (__attribute__((address_space(3))) void*)l, 16, 0, 0);
}

// ---------------- prep: fp32 -> bf16 casts + RoPE table (fused) ----------------
__global__ void k_prep(const float* __restrict__ x, const float* __restrict__ wq,
                       const float* __restrict__ wk, const float* __restrict__ wv,
                       const float* __restrict__ wo, const int* __restrict__ pos,
                       u16* __restrict__ xb, u16* __restrict__ wqkvb, u16* __restrict__ wob,
                       float2* __restrict__ tab) {
    int64_t i0 = (int64_t)blockIdx.x * blockDim.x + threadIdx.x;
    int64_t strd = (int64_t)gridDim.x * blockDim.x;
    const float4* x4 = (const float4*)x;
    ushort4* xb4 = (ushort4*)xb;
    for (int64_t t = i0; t < (int64_t)MROWS*DM/4; t += strd) {
        float4 v = x4[t];
        xb4[t] = make_ushort4(f2b(v.x), f2b(v.y), f2b(v.z), f2b(v.w));
    }
    const float4* q4 = (const float4*)wq;
    const float4* k4 = (const float4*)wk;
    const float4* v4 = (const float4*)wv;
    const float4* o4 = (const float4*)wo;
    ushort4* w4  = (ushort4*)wqkvb;
    ushort4* wo4 = (ushort4*)wob;
    const int64_t nw4 = (int64_t)DM*DM/4;   // 262144
    for (int64_t t = i0; t < nw4; t += strd) {
        float4 a = q4[t]; w4[t]         = make_ushort4(f2b(a.x), f2b(a.y), f2b(a.z), f2b(a.w));
        float4 b = k4[t]; w4[nw4 + t]   = make_ushort4(f2b(b.x), f2b(b.y), f2b(b.z), f2b(b.w));
        float4 c = v4[t]; w4[2*nw4 + t] = make_ushort4(f2b(c.x), f2b(c.y), f2b(c.z), f2b(c.w));
        float4 d = o4[t]; wo4[t]        = make_ushort4(f2b(d.x), f2b(d.y), f2b(d.z), f2b(d.w));
    }
    // RoPE cos/sin table: SS*32 entries
    for (int64_t t = i0; t < SS * 32; t += strd) {
        int s = (int)(t >> 5), j = (int)(t & 31);
        float p = (float)pos[s];
        float freq = powf(10000.0f, -(float)(2 * j) * (1.0f / 64.0f));
        float a = p * freq;
        tab[t] = make_float2(cosf(a), sinf(a));
    }
}

// ---------------- QKV projection GEMM: BK=32 + 2-phase dbuf ----------
// STAGE(t+1) issued BEFORE fragment reads / MFMA of tile t; ONE barrier per K-step.
__global__ void __launch_bounds__(256)
k_gemm_qkv(const u16* __restrict__ xb, const u16* __restrict__ wqkvb,
           const float2* __restrict__ tab,
           u16* __restrict__ Qb, u16* __restrict__ Kb, u16* __restrict__ Vt) {
    __shared__ u16 As[2][4096], Bs[2][4096];
    const int m0 = blockIdx.x * 128, n0 = blockIdx.y * 128;
    const int tid  = threadIdx.x;
    const int lane = tid & 63;
    const int wid  = tid >> 6;
    const int wm = (wid >> 1) << 6;
    const int wn = (wid & 1) << 6;
    const int lr = lane & 15;
    const int lg = lane >> 4;
    const int lk = lg << 3;

    f32x4 acc[4][4];
#pragma unroll
    for (int mi = 0; mi < 4; mi++)
#pragma unroll
        for (int ni = 0; ni < 4; ni++) acc[mi][ni] = f32x4{0.f, 0.f, 0.f, 0.f};

#define QSTAGE(kk, bb)                                                         \
    {                                                                          \
        _Pragma("unroll")                                                      \
        for (int iss = 0; iss < 2; ++iss) {                                    \
            int idx = iss * 2048 + tid * 8;                                    \
            int row = idx >> 5;                                                \
            int col = idx & 31;                                                \
            gload_lds16(xb    + (int64_t)(m0 + row) * 1024 + (kk) + col,       \
                        &As[bb][idx]);                                         \
            gload_lds16(wqkvb + (int64_t)(n0 + row) * 1024 + (kk) + col,       \
                        &Bs[bb][idx]);                                         \
        }                                                                      \
    }

    QSTAGE(0, 0)
    asm volatile("s_waitcnt vmcnt(0)" ::: "memory");
    __syncthreads();

    int cur = 0;
    for (int k0 = 0; k0 < 1024; k0 += 32) {
        if (k0 + 32 < 1024) QSTAGE(k0 + 32, cur ^ 1)   // prefetch next tile
        s16x8 af[4], bf[4];
#pragma unroll
        for (int mi = 0; mi < 4; mi++)
            af[mi] = *(const s16x8*)(&As[cur][0] + (wm + mi * 16 + lr) * 32 + lk);
#pragma unroll
        for (int ni = 0; ni < 4; ni++)
            bf[ni] = *(const s16x8*)(&Bs[cur][0] + (wn + ni * 16 + lr) * 32 + lk);
        __builtin_amdgcn_s_setprio(1);
#pragma unroll
        for (int mi = 0; mi < 4; mi++)
#pragma unroll
            for (int ni = 0; ni < 4; ni++)
                acc[mi][ni] = mfma16(af[mi], bf[ni], acc[mi][ni]);
        __builtin_amdgcn_s_setprio(0);
        __syncthreads();    // implicit vmcnt(0)+lgkmcnt(0) drain: next tile ready
        cur ^= 1;
    }
#undef QSTAGE

    // ---- fused RoPE + V-transpose epilogue ----
    const float QSC = 0.18033688011112042f;  // (1/8) * log2(e)
    const bool evenlane = (lr & 1) == 0;
#pragma unroll
    for (int mi = 0; mi < 4; mi++) {
        const int gm0 = m0 + wm + mi * 16 + lg * 4;
        const int b = gm0 >> 11;
        const int s0 = gm0 & 2047;
#pragma unroll
        for (int ni = 0; ni < 4; ni++) {
            int gn = n0 + wn + ni * 16 + lr;
            int which = gn >> 10;
            int nn = gn & 1023;
            int h = nn >> 6, d = nn & 63;
            if (which == 2) {
                ushort4 pk;
                pk.x = f2b(acc[mi][ni][0]);
                pk.y = f2b(acc[mi][ni][1]);
                pk.z = f2b(acc[mi][ni][2]);
                pk.w = f2b(acc[mi][ni][3]);
                *(ushort4*)(Vt + ((int64_t)(b * 16 + h)) * (2048 * 64)
                               + (int64_t)d * 2048 + s0) = pk;
            } else {
                u16* dst = (which == 0) ? Qb : Kb;
                float scl = (which == 0) ? QSC : 1.0f;
                int j = d >> 1;
#pragma unroll
                for (int r = 0; r < 4; r++) {
                    float v = acc[mi][ni][r];
                    float partner = __shfl_xor(v, 1, 64);
                    float2 cs = tab[(s0 + r) * 32 + j];
                    float outv = evenlane ? (cs.x * v - cs.y * partner)
                                          : (cs.y * partner + cs.x * v);
                    dst[(((int64_t)(b * 16 + h)) * 2048 + (s0 + r)) * 64 + d] =
                        f2b(outv * scl);
                }
            }
        }
    }
}

// ---------------- causal flash attention, single-buffered K/V, 24KB LDS ----------
__global__ void __launch_bounds__(128)
k_attn(const u16* __restrict__ Q, const u16* __restrict__ K,
       const u16* __restrict__ Vt, u16* __restrict__ O,
       u16* __restrict__ Op1, float* __restrict__ l0, float* __restrict__ l1) {
    __shared__ __align__(16) u16 Kl[4096];      // 64 keys x 64 d, swizzled (8KB)
    __shared__ __align__(16) u16 Vl[4096];      // 64 d x 64 keys, swizzled (8KB)
    __shared__ __align__(16) char Pbuf[2][4096];
    const int tid  = threadIdx.x;
    const int lane = tid & 63;
    const int wid  = tid >> 6;                  // 0..1
    const int lr = lane & 15;
    const int lg = lane >> 4;
    const int lk = lg * 8;
    const int G  = blockIdx.x >> 5;             // 0..47
    const int bh = blockIdx.x & 31;             // bh -> XCD bh%8
    int c, seg, split;
    if (G < 8)       { c = 15 - G;            seg = 0;     split = 0; }
    else if (G < 40) { int j = G - 8; c = 31 - (j >> 1); seg = j & 1; split = 1; }
    else             { c = 47 - G;            seg = 0;     split = 0; }
    const int T  = c + 1;                       // total tiles for this chunk
    const int h0 = T >> 1;
    const int t0 = (split && seg == 1) ? h0 : 0;
    const int nT = split ? (seg == 0 ? h0 : T - h0) : T;
    const int hasDiag = !(split && seg == 0);
    const int q0 = c * 64 + wid * 32;           // this wave's first q row
    const int64_t base = (int64_t)bh * (2048 * 64);
    const u16* Qp = Q  + base;
    const u16* Kp = K  + base;
    const u16* Vp = Vt + base;   // [d][s] layout

    s16x8 aq[2][2];
#pragma unroll
    for (int mi = 0; mi < 2; ++mi)
#pragma unroll
        for (int db = 0; db < 2; ++db)
            aq[mi][db] = *(const s16x8*)(Qp + (q0 + mi * 16 + lr) * 64 + db * 32 + lk);

    f32x4 acco[2][4];
    f32x4 accl[2];
#pragma unroll
    for (int mi = 0; mi < 2; ++mi) {
        accl[mi] = f32x4{0.f, 0.f, 0.f, 0.f};
#pragma unroll
        for (int df = 0; df < 4; ++df) acco[mi][df] = f32x4{0.f, 0.f, 0.f, 0.f};
    }
    const s16x8 ones = {(short)0x3F80, (short)0x3F80, (short)0x3F80, (short)0x3F80,
                        (short)0x3F80, (short)0x3F80, (short)0x3F80, (short)0x3F80};
    const int swz = (lr & 7) << 4;
    char* PwB = &Pbuf[wid][0];

#define STAGE(t)                                                               \
    {                                                                          \
        const u16* ks = Kp + (t) * 4096;                                       \
        const u16* vs = Vp + (t) * 64;                                         \
        _Pragma("unroll")                                                      \
        for (int p = 0; p < 4; ++p) {                                          \
            int o = p * 2048 + tid * 16;                                       \
            int row = o >> 7;                                                  \
            int cc = ((o >> 4) & 7) ^ (row & 7);                               \
            gload_lds16(ks + row * 64 + cc * 8,                                \
                        (u16*)((char*)&Kl[0] + o));                            \
            gload_lds16(vs + row * 2048 + cc * 8,                              \
                        (u16*)((char*)&Vl[0] + o));                            \
        }                                                                      \
    }

    STAGE(t0)

    for (int u = 0; u < nT; ++u) {
        const int t = t0 + u;
        asm volatile("s_waitcnt vmcnt(0)" ::: "memory");
        __syncthreads();                         // staged tile visible to both waves
        {
            const char* Kc = (const char*)&Kl[0];
            const char* Vc = (const char*)&Vl[0];
            // K fragments from LDS (swizzled)
            s16x8 bk[4][2];
#pragma unroll
            for (int kb = 0; kb < 4; ++kb)
#pragma unroll
                for (int db = 0; db < 2; ++db) {
                    int row = kb * 16 + lr;
                    int cc = (db * 4 + lg) ^ (row & 7);
                    bk[kb][db] = *(const s16x8*)(Kc + row * 128 + cc * 16);
                }
            // QK^T (SWAPPED: A=K, B=Q -> C[row=key_local, col=q_local])
            f32x4 sc[2][4];
            __builtin_amdgcn_s_setprio(1);
#pragma unroll
            for (int mi = 0; mi < 2; ++mi)
#pragma unroll
                for (int kb = 0; kb < 4; ++kb) {
                    sc[mi][kb] = f32x4{0.f, 0.f, 0.f, 0.f};
#pragma unroll
                    for (int db = 0; db < 2; ++db)
                        sc[mi][kb] = mfma16(bk[kb][db], aq[mi][db], sc[mi][kb]);
                }
            __builtin_amdgcn_s_setprio(0);
            // exp2 + packed P write
            const int k0 = t << 6;
            if (hasDiag && u == nT - 1) {
#pragma unroll
                for (int mi = 0; mi < 2; ++mi) {
                    const int prow = mi * 16 + lr;
                    const int qg = q0 + prow;
                    const int pswz = (prow & 7) << 4;
#pragma unroll
                    for (int kb = 0; kb < 4; ++kb) {
                        const int kg = k0 + kb * 16 + lg * 4;
                        float p0 = EXP2((kg     <= qg) ? sc[mi][kb][0] : -3.0e38f);
                        float p1 = EXP2((kg + 1 <= qg) ? sc[mi][kb][1] : -3.0e38f);
                        float p2 = EXP2((kg + 2 <= qg) ? sc[mi][kb][2] : -3.0e38f);
                        float p3 = EXP2((kg + 3 <= qg) ? sc[mi][kb][3] : -3.0e38f);
                        u32 lo = (u32)f2b(p0) | ((u32)f2b(p1) << 16);
                        u32 hi = (u32)f2b(p2) | ((u32)f2b(p3) << 16);
                        int bo = (prow << 7) + kb * 32 + (lg << 3);
                        *(uint2*)(PwB + (bo ^ pswz)) = make_uint2(lo, hi);
                    }
                }
            } else {
#pragma unroll
                for (int mi = 0; mi < 2; ++mi) {
                    const int prow = mi * 16 + lr;
                    const int pswz = (prow & 7) << 4;
#pragma unroll
                    for (int kb = 0; kb < 4; ++kb) {
                        float p0 = EXP2(sc[mi][kb][0]);
                        float p1 = EXP2(sc[mi][kb][1]);
                        float p2 = EXP2(sc[mi][kb][2]);
                        float p3 = EXP2(sc[mi][kb][3]);
                        u32 lo = (u32)f2b(p0) | ((u32)f2b(p1) << 16);
                        u32 hi = (u32)f2b(p2) | ((u32)f2b(p3) << 16);
                        int bo = (prow << 7) + kb * 32 + (lg << 3);
                        *(uint2*)(PwB + (bo ^ pswz)) = make_uint2(lo, hi);
                    }
                }
            }
            // V fragments from LDS (swizzled)
            s16x8 bv[2][4];
#pragma unroll
            for (int kc = 0; kc < 2; ++kc)
#pragma unroll
                for (int df = 0; df < 4; ++df) {
                    int row = df * 16 + lr;
                    int cc = (kc * 4 + lg) ^ (row & 7);
                    bv[kc][df] = *(const s16x8*)(Vc + row * 128 + cc * 16);
                }
            asm volatile("s_waitcnt lgkmcnt(0)" ::: "memory");
            // PV + row-sum via all-ones MFMA
            __builtin_amdgcn_s_setprio(1);
#pragma unroll
            for (int mi = 0; mi < 2; ++mi)
#pragma unroll
                for (int kc = 0; kc < 2; ++kc) {
                    int ro = ((mi * 16 + lr) << 7) + (kc << 6) + (lg << 4);
                    s16x8 ap = *(const s16x8*)(PwB + (ro ^ swz));
#pragma unroll
                    for (int df = 0; df < 4; ++df)
                        acco[mi][df] = mfma16(ap, bv[kc][df], acco[mi][df]);
                    accl[mi] = mfma16(ap, ones, accl[mi]);
                }
            __builtin_amdgcn_s_setprio(0);
        }
        __syncthreads();                         // both waves done reading K/V LDS
        if (u + 1 < nT) STAGE(t0 + u + 1)
    }
#undef STAGE

    // ---- epilogue ----
    const int b = bh >> 4, h = bh & 15;
    if (!split) {
#pragma unroll
        for (int mi = 0; mi < 2; ++mi) {
            float inv[4];
#pragma unroll
            for (int r = 0; r < 4; ++r) inv[r] = 1.0f / accl[mi][r];
#pragma unroll
            for (int df = 0; df < 4; ++df)
#pragma unroll
                for (int r = 0; r < 4; ++r) {
                    const int s = q0 + mi * 16 + lg * 4 + r;
                    const int d = df * 16 + lr;
                    O[(((int64_t)(b * 2048 + s)) * 16 + h) * 64 + d] =
                        f2b(acco[mi][df][r] * inv[r]);
                }
        }
    } else {
        const int cc = c - 16;
        const int rg0 = (bh * 16 + cc) * 64 + wid * 32;  // row-group base
        if (seg == 0) {
#pragma unroll
            for (int mi = 0; mi < 2; ++mi) {
#pragma unroll
                for (int df = 0; df < 4; ++df)
#pragma unroll
                    for (int r = 0; r < 4; ++r) {
                        const int s = q0 + mi * 16 + lg * 4 + r;
                        const int d = df * 16 + lr;
                        O[(((int64_t)(b * 2048 + s)) * 16 + h) * 64 + d] =
                            f2b(acco[mi][df][r]);
                    }
                if (lr == 0)
#pragma unroll
                    for (int r = 0; r < 4; ++r)
                        l0[rg0 + mi * 16 + lg * 4 + r] = accl[mi][r];
            }
        } else {
#pragma unroll
            for (int mi = 0; mi < 2; ++mi) {
#pragma unroll
                for (int df = 0; df < 4; ++df)
#pragma unroll
                    for (int r = 0; r < 4; ++r) {
                        const int row = wid * 32 + mi * 16 + lg * 4 + r;
                        const int d = df * 16 + lr;
                        Op1[((int64_t)((bh * 16 + cc) * 64 + row)) * 64 + d] =
                            f2b(acco[mi][df][r]);
                    }
                if (lr == 0)
#pragma unroll
                    for (int r = 0; r < 4; ++r)
                        l1[rg0 + mi * 16 + lg * 4 + r] = accl[mi][r];
            }
        }
    }
}

// ---------------- combine split-KV partials: O = (O + Op1) / (l0 + l1) ----------------
__global__ void __launch_bounds__(256)
k_combine(u16* __restrict__ O, const u16* __restrict__ Op1,
          const float* __restrict__ l0, const float* __restrict__ l1) {
    int i = blockIdx.x * 256 + threadIdx.x;     // 0..262143
    int rg = i >> 3;                            // (bh,cc,row) 0..32767
    int d0 = (i & 7) << 3;
    int bh = rg >> 10;
    int cc = (rg >> 6) & 15;
    int row = rg & 63;
    float inv = 1.0f / (l0[rg] + l1[rg]);
    int b = bh >> 4, h = bh & 15;
    int s = (16 + cc) * 64 + row;
    u16* op = O + (((int64_t)(b * 2048 + s)) * 16 + h) * 64 + d0;
    const u16* sp = Op1 + (int64_t)rg * 64 + d0;
    s16x8 a = *(const s16x8*)op;
    s16x8 bb = *(const s16x8*)sp;
    u16 outv[8];
#pragma unroll
    for (int j = 0; j < 8; ++j)
        outv[j] = f2b((b2f((u16)a[j]) + b2f((u16)bb[j])) * inv);
    *(s16x8*)op = *(s16x8*)&outv[0];
}

// ---------------- output projection GEMM: 64x128 tiles, 2-phase dbuf ----------
__global__ void __launch_bounds__(256)
k_gemm_out(const u16* __restrict__ Ob, const u16* __restrict__ wob, float* __restrict__ out) {
    __shared__ u16 As[2][2048], Bs[2][4096];   // 64x32 A, 128x32 B, double-buffered
    const int m0 = blockIdx.x * 64, n0 = blockIdx.y * 128;
    const int tid  = threadIdx.x;
    const int lane = tid & 63;
    const int wid  = tid >> 6;          // 4 waves, each 64x32 output (wn = wid*32)
    const int wn = wid << 5;
    const int lr = lane & 15;
    const int lk = (lane >> 4) << 3;
    f32x4 acc[4][2];
#pragma unroll
    for (int mi = 0; mi < 4; mi++)
#pragma unroll
        for (int ni = 0; ni < 2; ni++) acc[mi][ni] = f32x4{0.f, 0.f, 0.f, 0.f};

#define OSTAGE(kk, bb)                                                         \
    {                                                                          \
        {   int idx = tid * 8;                                                 \
            int row = idx >> 5, col = idx & 31;                                \
            gload_lds16(Ob + (int64_t)(m0 + row) * 1024 + (kk) + col,          \
                        &As[bb][idx]); }                                       \
        _Pragma("unroll")                                                      \
        for (int iss = 0; iss < 2; ++iss) {                                    \
            int idx = iss * 2048 + tid * 8;                                    \
            int row = idx >> 5, col = idx & 31;                                \
            gload_lds16(wob + (int64_t)(n0 + row) * 1024 + (kk) + col,         \
                        &Bs[bb][idx]);                                         \
        }                                                                      \
    }

    OSTAGE(0, 0)
    asm volatile("s_waitcnt vmcnt(0)" ::: "memory");
    __syncthreads();

    int cur = 0;
    for (int k0 = 0; k0 < 1024; k0 += 32) {
        if (k0 + 32 < 1024) OSTAGE(k0 + 32, cur ^ 1)
        s16x8 af[4], bf[2];
#pragma unroll
        for (int mi = 0; mi < 4; mi++)
            af[mi] = *(const s16x8*)(&As[cur][0] + (mi * 16 + lr) * 32 + lk);
#pragma unroll
        for (int ni = 0; ni < 2; ni++)
            bf[ni] = *(const s16x8*)(&Bs[cur][0] + (wn + ni * 16 + lr) * 32 + lk);
        __builtin_amdgcn_s_setprio(1);
#pragma unroll
        for (int mi = 0; mi < 4; mi++)
#pragma unroll
            for (int ni = 0; ni < 2; ni++)
                acc[mi][ni] = mfma16(af[mi], bf[ni], acc[mi][ni]);
        __builtin_amdgcn_s_setprio(0);
        __syncthreads();
        cur ^= 1;
    }
#undef OSTAGE

    const int lg = lane >> 4;
#pragma unroll
    for (int mi = 0; mi < 4; mi++)
#pragma unroll
        for (int ni = 0; ni < 2; ni++) {
            int gn = n0 + wn + ni * 16 + lr;
#pragma unroll
            for (int r = 0; r < 4; r++) {
                int gm = m0 + mi * 16 + lg * 4 + r;
                out[(int64_t)gm * 1024 + gn] = acc[mi][ni][r];
            }
        }
}

extern "C" void kernel_launch(void* const* d_in, const int* in_sizes, int n_in,
                              void* d_out, int out_size, void* d_ws, size_t ws_size,
                              hipStream_t stream) {
    const float* x  = (const float*)d_in[0];
    const int* pos  = (const int*)d_in[1];
    const float* wq = (const float*)d_in[2];
    const float* wk = (const float*)d_in[3];
    const float* wv = (const float*)d_in[4];
    const float* wo = (const float*)d_in[5];
    float* out = (float*)d_out;

    char* w = (char*)d_ws;
    u16* xb    = (u16*)w;    w += (size_t)MROWS * DM * 2;        // 8 MB
    u16* wqkvb = (u16*)w;    w += (size_t)3 * DM * DM * 2;       // 6 MB
    u16* wob   = (u16*)w;    w += (size_t)DM * DM * 2;           // 2 MB
    float2* tab = (float2*)w; w += (size_t)SS * 32 * sizeof(float2); // 512 KB
    u16* Qb = (u16*)w;       w += (size_t)MROWS * DM * 2;        // 8 MB
    u16* Kb = (u16*)w;       w += (size_t)MROWS * DM * 2;        // 8 MB
    u16* Vt = (u16*)w;       w += (size_t)MROWS * DM * 2;        // 8 MB
    u16* Ob = (u16*)w;                                           // 8 MB
    // split-KV scratch carved from xb (dead after k_gemm_qkv): 4MB + 128KB + 128KB
    u16*   Op1 = xb;                                  // 32*16*64*64 bf16 = 4 MB
    float* l0  = (float*)((char*)xb + (4 << 20));     // 128 KB
    float* l1  = (float*)((char*)xb + (4 << 20) + (128 << 10));

    k_prep<<<dim3(1024), dim3(256), 0, stream>>>(x, wq, wk, wv, wo, pos,
                                                 xb, wqkvb, wob, tab);
    k_gemm_qkv<<<dim3(32, 24), dim3(256), 0, stream>>>(xb, wqkvb, tab, Qb, Kb, Vt);
    k_attn<<<dim3(1536), dim3(128), 0, stream>>>(Qb, Kb, Vt, Ob, Op1, l0, l1);
    k_combine<<<dim3(1024), dim3(256), 0, stream>>>(Ob, Op1, l0, l1);
    k_gemm_out<<<dim3(64, 8), dim3(256), 0, stream>>>(Ob, wob, out);
}